// Round 7
// baseline (1092.773 us; speedup 1.0000x reference)
//
#include <hip/hip_runtime.h>
#include <hip/hip_bf16.h>

#define B_ 2
#define T_ 32768
#define CH_ 128
#define EC_ 512
#define ATOM_ 2048
#define FBK_ 512

typedef __attribute__((ext_vector_type(8))) short s16x8;
typedef __attribute__((ext_vector_type(8))) _Float16 f16x8;
typedef __attribute__((ext_vector_type(4))) float f32x4;

__device__ __forceinline__ f16x8 ldh8(const _Float16* p) {
    union { s16x8 s; f16x8 h; } u; u.s = *(const s16x8*)p; return u.h;
}

// ---------------- MFMA filter bank: x[b,1,T] -> spec16[b][t][band] f16 ----------------
__global__ void __launch_bounds__(256) k_fbm(const float* __restrict__ x,
        const _Float16* __restrict__ Wfb, _Float16* __restrict__ spec16) {
    __shared__ _Float16 XA[128][72];
    __shared__ float xw[640];
    int tid = threadIdx.x;
    int lane = tid & 63;
    int wv = tid >> 6, wm = wv >> 1, wn = wv & 1;
    int ln15 = lane & 15, kh = lane >> 4;
    int t0 = blockIdx.x * 128;
    int b = blockIdx.y;

    for (int i = tid; i < 640; i += 256) {
        int g = t0 - 256 + i;
        xw[i] = (g >= 0 && g < T_) ? x[(size_t)b*T_ + g] : 0.f;
    }

    f32x4 acc[4][4];
    f32x4 zero = {0.f,0.f,0.f,0.f};
#pragma unroll
    for (int m = 0; m < 4; ++m)
#pragma unroll
        for (int n = 0; n < 4; ++n) acc[m][n] = zero;

    for (int c = 0; c < 8; ++c) {
        int k0 = c*64;
        __syncthreads();               // xw ready on c==0; XA WAR on c>0
#pragma unroll
        for (int q = 0; q < 4; ++q) {
            int idx = tid + q*256;
            int r = idx >> 3, ko = idx & 7;
            int base = r + k0 + ko*8;
            f16x8 v;
#pragma unroll
            for (int j = 0; j < 8; ++j) v[j] = (_Float16)xw[base + j];
            union { f16x8 h; s16x8 s; } u; u.h = v;
            *(s16x8*)&XA[r][ko*8] = u.s;
        }
        __syncthreads();
#pragma unroll
        for (int kt = 0; kt < 2; ++kt) {
            f16x8 af[4], bf[4];
#pragma unroll
            for (int m = 0; m < 4; ++m) af[m] = ldh8(&XA[wm*64+m*16+ln15][kt*32+kh*8]);
#pragma unroll
            for (int n = 0; n < 4; ++n)
                bf[n] = ldh8(Wfb + (size_t)(wn*64+n*16+ln15)*FBK_ + k0 + kt*32 + kh*8);
#pragma unroll
            for (int m = 0; m < 4; ++m)
#pragma unroll
                for (int n = 0; n < 4; ++n)
                    acc[m][n] = __builtin_amdgcn_mfma_f32_16x16x32_f16(af[m], bf[n], acc[m][n], 0,0,0);
        }
    }
#pragma unroll
    for (int mf = 0; mf < 4; ++mf)
#pragma unroll
        for (int nf = 0; nf < 4; ++nf) {
            int band = wn*64 + nf*16 + ln15;
#pragma unroll
            for (int j = 0; j < 4; ++j) {
                int tl = wm*64 + mf*16 + kh*4 + j;
                spec16[((size_t)b*T_ + t0 + tl)*CH_ + band] = (_Float16)acc[mf][nf][j];
            }
        }
}

// ---------------- weight prep ----------------
__global__ void k_pw7(const float* __restrict__ w, _Float16* __restrict__ W7) {
    int i = blockIdx.x*256+threadIdx.x;
    if (i >= 7*16384) return;
    int k = i / 16384, r = i % 16384; int co = r >> 7, ci = r & 127;
    W7[i] = (_Float16)w[(co*CH_+ci)*7 + k];
}
__global__ void k_pwd(const float* __restrict__ w, _Float16* __restrict__ Wd) {
    int i = blockIdx.x*256+threadIdx.x;
    if (i >= 7*3*16384) return;
    int st = i / 49152, r = i % 49152; int k = r / 16384, r2 = r % 16384;
    int co = r2 >> 7, ci = r2 & 127;
    Wd[i] = (_Float16)w[((size_t)(st*CH_+co)*CH_+ci)*3 + k];
}
__global__ void k_cast(const float* __restrict__ in, _Float16* __restrict__ out, int n) {
    int i = blockIdx.x*256+threadIdx.x;
    if (i < n) out[i] = (_Float16)in[i];
}
__global__ void k_zero(float* __restrict__ p, int n) {
    int i = blockIdx.x*256+threadIdx.x;
    if (i < n) p[i] = 0.f;
}

// ---------------- fused MFMA conv block (weights direct from global/L2) ----------------
template<int NTAP, bool NORM, bool PW, bool LRELU, bool RELU, bool STATS>
__global__ void __launch_bounds__(256) k_cv(
        const _Float16* __restrict__ in, const _Float16* __restrict__ W,
        const float* __restrict__ bias, const _Float16* __restrict__ Wp_,
        const float* __restrict__ pbias, const float* __restrict__ stats_in,
        const float* __restrict__ g, const float* __restrict__ bb,
        float* __restrict__ stats_out, _Float16* __restrict__ outp,
        int dil, int ostride) {
    __shared__ _Float16 XT[128][136];
    __shared__ _Float16 Y1[PW?128:1][PW?136:1];
    __shared__ float AffA[NORM?128:1], AffB[NORM?128:1];

    int tid = threadIdx.x;
    int lane = tid & 63;
    int wv = tid >> 6, wm = wv >> 1, wn = wv & 1;
    int ln15 = lane & 15, kh = lane >> 4;
    int t0 = blockIdx.x * 128;
    int nch = blockIdx.y;
    int b = blockIdx.z;
    int ncol0 = nch * 128;
    const _Float16* inb = in + (size_t)b*T_*CH_;
    const _Float16* W_eff = W + (size_t)ncol0*CH_;
    const float* bias_eff = bias + ncol0;

    if (NORM) {
        if (tid < 128) {
            const float invN = 1.f/(float)(B_*T_);
            float s1 = stats_in[tid], s2 = stats_in[128+tid];
            float m = s1*invN, var = s2*invN - m*m;
            float A = rsqrtf(var + 1e-5f) * g[tid];
            AffA[tid] = A; AffB[tid] = bb[tid] - m*A;
        }
    }

    f32x4 acc[4][4];
    f32x4 zero = {0.f,0.f,0.f,0.f};
#pragma unroll
    for (int m = 0; m < 4; ++m)
#pragma unroll
        for (int n = 0; n < 4; ++n) acc[m][n] = zero;

    for (int tap = 0; tap < NTAP; ++tap) {
        int tp = tap;
        if (PW) tp = (tap==0) ? 0 : ((tap==1) ? 2 : 1);   // center tap LAST (kept for residual)
        int off = (tp - NTAP/2)*dil;
        const _Float16* Wt = W_eff + (size_t)tp*CH_*CH_;
        __syncthreads();               // AffA ready (tap0) / XT WAR (tap>0)
#pragma unroll
        for (int q = 0; q < 8; ++q) {
            int idx = tid + q*256;
            int lt = idx >> 4, ck = idx & 15;
            int gt = t0 + lt + off;
            s16x8 v = {0,0,0,0,0,0,0,0};
            bool valid = (gt >= 0 && gt < T_);
            if (valid) {
                v = *(const s16x8*)(inb + (size_t)gt*CH_ + ck*8);
                if (NORM) {
                    union {s16x8 s; f16x8 h;} u; u.s = v;
                    f16x8 r;
#pragma unroll
                    for (int j = 0; j < 8; ++j) {
                        float f = (float)u.h[j];
                        f = fmaf(f, AffA[ck*8+j], AffB[ck*8+j]);
                        r[j] = (_Float16)f;
                    }
                    union {f16x8 h; s16x8 s;} w2; w2.h = r; v = w2.s;
                }
            }
            *(s16x8*)&XT[lt][ck*8] = v;
        }
        __syncthreads();
#pragma unroll
        for (int kt = 0; kt < 4; ++kt) {
            f16x8 af[4], bf[4];
#pragma unroll
            for (int m = 0; m < 4; ++m) af[m] = ldh8(&XT[wm*64+m*16+ln15][kt*32+kh*8]);
#pragma unroll
            for (int n = 0; n < 4; ++n)
                bf[n] = ldh8(Wt + (size_t)(wn*64+n*16+ln15)*CH_ + kt*32 + kh*8);
#pragma unroll
            for (int m = 0; m < 4; ++m)
#pragma unroll
                for (int n = 0; n < 4; ++n)
                    acc[m][n] = __builtin_amdgcn_mfma_f32_16x16x32_f16(af[m], bf[n], acc[m][n], 0,0,0);
        }
    }

    if (PW) {
#pragma unroll
        for (int mf = 0; mf < 4; ++mf)
#pragma unroll
            for (int nf = 0; nf < 4; ++nf) {
                int co = wn*64 + nf*16 + ln15;
                float bv = bias_eff[co];
#pragma unroll
                for (int j = 0; j < 4; ++j) {
                    int tl = wm*64 + mf*16 + kh*4 + j;
                    Y1[tl][co] = (_Float16)(acc[mf][nf][j] + bv);
                }
            }
#pragma unroll
        for (int m = 0; m < 4; ++m)
#pragma unroll
            for (int n = 0; n < 4; ++n) acc[m][n] = zero;
        __syncthreads();
#pragma unroll
        for (int kt = 0; kt < 4; ++kt) {
            f16x8 af[4], bf[4];
#pragma unroll
            for (int m = 0; m < 4; ++m) af[m] = ldh8(&Y1[wm*64+m*16+ln15][kt*32+kh*8]);
#pragma unroll
            for (int n = 0; n < 4; ++n)
                bf[n] = ldh8(Wp_ + (size_t)(wn*64+n*16+ln15)*CH_ + kt*32 + kh*8);
#pragma unroll
            for (int m = 0; m < 4; ++m)
#pragma unroll
                for (int n = 0; n < 4; ++n)
                    acc[m][n] = __builtin_amdgcn_mfma_f32_16x16x32_f16(af[m], bf[n], acc[m][n], 0,0,0);
        }
    }

#pragma unroll
    for (int nf = 0; nf < 4; ++nf) {
        int co = wn*64 + nf*16 + ln15;
        float bfin = PW ? pbias[co] : bias_eff[co];
        float s = 0.f, s2 = 0.f;
#pragma unroll
        for (int mf = 0; mf < 4; ++mf) {
#pragma unroll
            for (int j = 0; j < 4; ++j) {
                int tl = wm*64 + mf*16 + kh*4 + j;
                float v = acc[mf][nf][j] + bfin;
                if (PW) v += (float)XT[tl][co];    // residual = normalized center tile
                if (LRELU) v = v >= 0.f ? v : 0.2f*v;
                if (RELU)  v = fmaxf(v, 0.f);
                outp[((size_t)b*T_ + t0 + tl)*ostride + ncol0 + co] = (_Float16)v;
                if (STATS) { s += v; s2 += v*v; }
            }
        }
        if (STATS) {
            s  += __shfl_down(s, 16);  s  += __shfl_down(s, 32);
            s2 += __shfl_down(s2, 16); s2 += __shfl_down(s2, 32);
            if (kh == 0) {
                atomicAdd(&stats_out[co], s);
                atomicAdd(&stats_out[128+co], s2);
            }
        }
    }
}

// ---------------- transpose static_dict [512][2048] fp32 -> At [2048][512] f16 ----------------
__global__ void k_tr_at(const float* __restrict__ sd, _Float16* __restrict__ At) {
    __shared__ float tile[32][33];
    int tau0 = blockIdx.x*32;
    int c0 = blockIdx.y*32;
    int tx = threadIdx.x, ty = threadIdx.y;
#pragma unroll
    for (int j = 0; j < 4; ++j)
        tile[ty+j*8][tx] = sd[(size_t)(c0+ty+j*8)*ATOM_ + tau0 + tx];
    __syncthreads();
#pragma unroll
    for (int j = 0; j < 4; ++j)
        At[(size_t)(tau0+ty+j*8)*EC_ + c0 + tx] = (_Float16)tile[tx][ty+j*8];
}

// ---------------- dictionary conv: E-resident GEMM, stream At, fused anti-diag ----------------
// block = one 128-row s-slice (and batch); loop all 16 tau-tiles x 8 c-chunks = 128 K-steps.
// out[b][128*sT + 128*tt + taul + sl] += At[..][c] * enc[..][c]
__global__ void __launch_bounds__(512) k_gemm(const _Float16* __restrict__ At,
                                              const _Float16* __restrict__ enc,
                                              float* __restrict__ out) {
    __shared__ _Float16 lE[128][520];   // enc tile, padded (+8): row stride 1040B -> 2-way max
    __shared__ _Float16 lA[128][72];    // At chunk, padded (+8): row stride 144B
    __shared__ float pt[2176];          // anti-diag accumulator (2048+127 used)
    int tid = threadIdx.x;
    int lane = tid & 63;
    int wv = tid >> 6;        // 0..7
    int wm = wv >> 2;         // 0..1 : tau 64-block
    int wn = wv & 3;          // 0..3 : s 32-block
    int sT = blockIdx.x;
    int b  = blockIdx.y;
    const _Float16* Eb = enc + ((size_t)b*T_ + (size_t)sT*128)*EC_;
    int ln15 = lane & 15, kh = lane >> 4;

    for (int i = tid; i < 2176; i += 512) pt[i] = 0.f;
    // stage resident E tile 128x512 (once)
#pragma unroll
    for (int q = 0; q < 16; ++q) {
        int idx = tid + q*512;
        int r = idx >> 6, c8 = (idx & 63) << 3;
        s16x8 v = *(const s16x8*)(Eb + (size_t)r*EC_ + c8);
        *(s16x8*)&lE[r][c8] = v;
    }

    f32x4 acc[4][2];
    f32x4 zero = {0.f,0.f,0.f,0.f};
#pragma unroll
    for (int m = 0; m < 4; ++m) { acc[m][0] = zero; acc[m][1] = zero; }

    // T14 async-split: prefetch A chunk c to regs, write after WAR barrier, load c+1
    s16x8 p0, p1;
    {
        int i0 = tid, i1 = tid + 512;
        p0 = *(const s16x8*)(At + (size_t)(i0 >> 3)*EC_ + ((i0 & 7) << 3));
        p1 = *(const s16x8*)(At + (size_t)(i1 >> 3)*EC_ + ((i1 & 7) << 3));
    }
    for (int c = 0; c < 128; ++c) {
        __syncthreads();                        // WAR on lA (covers lE/pt init on c==0)
        {
            int i0 = tid, i1 = tid + 512;
            *(s16x8*)&lA[i0 >> 3][(i0 & 7) << 3] = p0;
            *(s16x8*)&lA[i1 >> 3][(i1 & 7) << 3] = p1;
        }
        {
            int nc = (c + 1) & 127;
            int bt = (nc >> 3) * 128, bk = (nc & 7) * 64;
            int i0 = tid, i1 = tid + 512;
            p0 = *(const s16x8*)(At + (size_t)(bt + (i0 >> 3))*EC_ + bk + ((i0 & 7) << 3));
            p1 = *(const s16x8*)(At + (size_t)(bt + (i1 >> 3))*EC_ + bk + ((i1 & 7) << 3));
        }
        __syncthreads();                        // lA ready
        int kt = c & 7;
#pragma unroll
        for (int kk = 0; kk < 2; ++kk) {
            f16x8 af[4], bf[2];
#pragma unroll
            for (int m = 0; m < 4; ++m)
                af[m] = ldh8(&lA[wm*64 + m*16 + ln15][kk*32 + kh*8]);
#pragma unroll
            for (int n = 0; n < 2; ++n)
                bf[n] = ldh8(&lE[wn*32 + n*16 + ln15][kt*64 + kk*32 + kh*8]);
#pragma unroll
            for (int m = 0; m < 4; ++m)
#pragma unroll
                for (int n = 0; n < 2; ++n)
                    acc[m][n] = __builtin_amdgcn_mfma_f32_16x16x32_f16(af[m], bf[n], acc[m][n], 0, 0, 0);
        }
        if ((c & 7) == 7) {                     // tau-tile done: anti-diag reduce into pt
            int tt = c >> 3;
#pragma unroll
            for (int mn = 0; mn <= 4; ++mn) {
#pragma unroll
                for (int j = 0; j < 4; ++j) {
                    float v = 0.f;
#pragma unroll
                    for (int n = 0; n < 2; ++n) {
                        int m = mn - n;
                        if (m >= 0 && m < 4) v += acc[m][n][j];
                    }
                    int tl = wm*64 + wn*32 + mn*16 + kh*4 + j + ln15;
                    unsafeAtomicAdd(&pt[tt*128 + tl], v);
                }
            }
#pragma unroll
            for (int m = 0; m < 4; ++m) { acc[m][0] = zero; acc[m][1] = zero; }
        }
    }
    __syncthreads();
    for (int i = tid; i < 2175; i += 512) {
        int t = sT*128 + i;
        if (t < T_) unsafeAtomicAdd(&out[(size_t)b*T_ + t], pt[i]);
    }
}

__global__ void k_fill(float* __restrict__ out, float val) {
    out[blockIdx.x*256 + threadIdx.x] = val;
}

extern "C" void kernel_launch(void* const* d_in, const int* in_sizes, int n_in,
                              void* d_out, int out_size, void* d_ws, size_t ws_size,
                              hipStream_t stream) {
    const float* x       = (const float*)d_in[0];
    const float* fb_w    = (const float*)d_in[1];
    const float* conv0_w = (const float*)d_in[2];
    const float* conv0_b = (const float*)d_in[3];
    const float* bn0_g   = (const float*)d_in[4];
    const float* bn0_b   = (const float*)d_in[5];
    const float* dil_w   = (const float*)d_in[6];
    const float* dil_b   = (const float*)d_in[7];
    const float* pw_w    = (const float*)d_in[8];
    const float* pw_b    = (const float*)d_in[9];
    const float* bn_g    = (const float*)d_in[10];
    const float* bn_b    = (const float*)d_in[11];
    const float* up_w    = (const float*)d_in[12];
    const float* up_b    = (const float*)d_in[13];
    const float* sdict   = (const float*)d_in[14];
    float* out = (float*)d_out;
    char* ws = (char*)d_ws;

    // layout (bytes)
    const size_t R1   = 33554432;   // spec16 -> enc[0]
    const size_t R2   = 33554432;   // enc[1]  (enc = r1, 67MB contiguous)
    const size_t ACT  = 16777216;   // f16 [b][t][c]
    char* r1   = ws;
    char* actA = ws + R1 + R2;
    char* actB = actA + ACT;
    char* wreg = actB + ACT;
    _Float16* W7   = (_Float16*)wreg;                      // 7*16384
    _Float16* Wd   = W7 + 7*16384;                         // 7*3*16384
    _Float16* Wp   = Wd + 7*3*16384;                       // 7*16384
    _Float16* Wup  = Wp + 7*16384;                         // 65536
    _Float16* Wfb  = Wup + 65536;                          // 65536
    float* stats   = (float*)(Wfb + 65536);                // 8*2*128 floats
    const size_t TOTAL = R1 + R2 + 2*ACT
                       + (7*16384 + 7*3*16384 + 7*16384 + 65536 + 65536)*2 + 8*2*128*4;
    if (ws_size < TOTAL) {
        k_fill<<<(out_size+255)/256, 256, 0, stream>>>(out, 12345.0f);
        return;
    }
    _Float16* spec16 = (_Float16*)r1;
    _Float16* enc = (_Float16*)r1;            // [b][t][c], 67MB (spec16 dead after conv0)
    _Float16* At  = (_Float16*)(actA + 2097152);  // alias in actA (free after conv stack)

    // prep
    k_zero<<<(2048+255)/256, 256, 0, stream>>>(stats, 8*2*128);
    k_pw7<<<(7*16384+255)/256, 256, 0, stream>>>(conv0_w, W7);
    k_pwd<<<(7*3*16384+255)/256, 256, 0, stream>>>(dil_w, Wd);
    k_cast<<<(7*16384+255)/256, 256, 0, stream>>>(pw_w, Wp, 7*16384);
    k_cast<<<(65536+255)/256, 256, 0, stream>>>(up_w, Wup, 65536);
    k_cast<<<(65536+255)/256, 256, 0, stream>>>(fb_w, Wfb, 65536);

    // front: MFMA filter bank, direct time-major f16
    k_fbm<<<dim3(T_/128, B_), 256, 0, stream>>>(x, Wfb, spec16);
    k_cv<7,false,false,true,false,true><<<dim3(T_/128,1,B_), 256, 0, stream>>>(
        spec16, W7, conv0_b, nullptr, nullptr, nullptr, nullptr, nullptr,
        stats + 0, (_Float16*)actA, 1, CH_);

    const int DILS[7] = {1, 3, 9, 27, 81, 243, 1};
    _Float16* cur = (_Float16*)actA;
    _Float16* nxt = (_Float16*)actB;
    for (int i = 0; i < 7; ++i) {
        const float* gi = (i == 0) ? bn0_g : bn_g + (i-1)*CH_;
        const float* bi = (i == 0) ? bn0_b : bn_b + (i-1)*CH_;
        k_cv<3,true,true,true,false,true><<<dim3(T_/128,1,B_), 256, 0, stream>>>(
            cur, Wd + (size_t)i*3*CH_*CH_, dil_b + i*CH_, Wp + (size_t)i*CH_*CH_,
            pw_b + i*CH_, stats + i*256, gi, bi, stats + (i+1)*256, nxt, DILS[i], CH_);
        _Float16* sw = cur; cur = nxt; nxt = sw;
    }
    // cur == actB; actA free -> At alias valid; r1/r2 free for enc (both batches)

    k_tr_at<<<dim3(ATOM_/32, EC_/32), dim3(32,8), 0, stream>>>(sdict, At);
    // up-projection + relu -> enc[b][t][c] f16 (both batches)
    k_cv<1,true,false,false,true,false><<<dim3(T_/128,EC_/128,B_), 256, 0, stream>>>(
        cur, Wup, up_b, nullptr, nullptr,
        stats + 7*256, bn_g + 6*CH_, bn_b + 6*CH_, nullptr, enc, 1, EC_);

    // dictionary conv: zero out, then E-resident GEMM with fused anti-diagonal
    k_zero<<<(B_*T_+255)/256, 256, 0, stream>>>(out, B_*T_);
    k_gemm<<<dim3(T_/128, B_), 512, 0, stream>>>(At, enc, out);
}

// Round 8
// 930.295 us; speedup vs baseline: 1.1747x; 1.1747x over previous
//
#include <hip/hip_runtime.h>
#include <hip/hip_bf16.h>

#define B_ 2
#define T_ 32768
#define CH_ 128
#define EC_ 512
#define ATOM_ 2048
#define FBK_ 512

typedef __attribute__((ext_vector_type(8))) short s16x8;
typedef __attribute__((ext_vector_type(8))) _Float16 f16x8;
typedef __attribute__((ext_vector_type(4))) float f32x4;

__device__ __forceinline__ f16x8 ldh8(const _Float16* p) {
    union { s16x8 s; f16x8 h; } u; u.s = *(const s16x8*)p; return u.h;
}

__device__ __forceinline__ void gl_lds16(const _Float16* g, _Float16* l) {
    __builtin_amdgcn_global_load_lds(
        (const __attribute__((address_space(1))) unsigned int*)(g),
        (__attribute__((address_space(3))) unsigned int*)(l), 16, 0, 0);
}

// ---------------- MFMA filter bank: x[b,1,T] -> spec16[b][t][band] f16 ----------------
__global__ void __launch_bounds__(256) k_fbm(const float* __restrict__ x,
        const _Float16* __restrict__ Wfb, _Float16* __restrict__ spec16) {
    __shared__ _Float16 XA[128][72];
    __shared__ float xw[640];
    int tid = threadIdx.x;
    int lane = tid & 63;
    int wv = tid >> 6, wm = wv >> 1, wn = wv & 1;
    int ln15 = lane & 15, kh = lane >> 4;
    int t0 = blockIdx.x * 128;
    int b = blockIdx.y;

    for (int i = tid; i < 640; i += 256) {
        int g = t0 - 256 + i;
        xw[i] = (g >= 0 && g < T_) ? x[(size_t)b*T_ + g] : 0.f;
    }

    f32x4 acc[4][4];
    f32x4 zero = {0.f,0.f,0.f,0.f};
#pragma unroll
    for (int m = 0; m < 4; ++m)
#pragma unroll
        for (int n = 0; n < 4; ++n) acc[m][n] = zero;

    for (int c = 0; c < 8; ++c) {
        int k0 = c*64;
        __syncthreads();               // xw ready on c==0; XA WAR on c>0
#pragma unroll
        for (int q = 0; q < 4; ++q) {
            int idx = tid + q*256;
            int r = idx >> 3, ko = idx & 7;
            int base = r + k0 + ko*8;
            f16x8 v;
#pragma unroll
            for (int j = 0; j < 8; ++j) v[j] = (_Float16)xw[base + j];
            union { f16x8 h; s16x8 s; } u; u.h = v;
            *(s16x8*)&XA[r][ko*8] = u.s;
        }
        __syncthreads();
#pragma unroll
        for (int kt = 0; kt < 2; ++kt) {
            f16x8 af[4], bf[4];
#pragma unroll
            for (int m = 0; m < 4; ++m) af[m] = ldh8(&XA[wm*64+m*16+ln15][kt*32+kh*8]);
#pragma unroll
            for (int n = 0; n < 4; ++n)
                bf[n] = ldh8(Wfb + (size_t)(wn*64+n*16+ln15)*FBK_ + k0 + kt*32 + kh*8);
#pragma unroll
            for (int m = 0; m < 4; ++m)
#pragma unroll
                for (int n = 0; n < 4; ++n)
                    acc[m][n] = __builtin_amdgcn_mfma_f32_16x16x32_f16(af[m], bf[n], acc[m][n], 0,0,0);
        }
    }
#pragma unroll
    for (int mf = 0; mf < 4; ++mf)
#pragma unroll
        for (int nf = 0; nf < 4; ++nf) {
            int band = wn*64 + nf*16 + ln15;
#pragma unroll
            for (int j = 0; j < 4; ++j) {
                int tl = wm*64 + mf*16 + kh*4 + j;
                spec16[((size_t)b*T_ + t0 + tl)*CH_ + band] = (_Float16)acc[mf][nf][j];
            }
        }
}

// ---------------- weight prep ----------------
__global__ void k_pw7(const float* __restrict__ w, _Float16* __restrict__ W7) {
    int i = blockIdx.x*256+threadIdx.x;
    if (i >= 7*16384) return;
    int k = i / 16384, r = i % 16384; int co = r >> 7, ci = r & 127;
    W7[i] = (_Float16)w[(co*CH_+ci)*7 + k];
}
__global__ void k_pwd(const float* __restrict__ w, _Float16* __restrict__ Wd) {
    int i = blockIdx.x*256+threadIdx.x;
    if (i >= 7*3*16384) return;
    int st = i / 49152, r = i % 49152; int k = r / 16384, r2 = r % 16384;
    int co = r2 >> 7, ci = r2 & 127;
    Wd[i] = (_Float16)w[((size_t)(st*CH_+co)*CH_+ci)*3 + k];
}
__global__ void k_cast(const float* __restrict__ in, _Float16* __restrict__ out, int n) {
    int i = blockIdx.x*256+threadIdx.x;
    if (i < n) out[i] = (_Float16)in[i];
}
__global__ void k_zero(float* __restrict__ p, int n) {
    int i = blockIdx.x*256+threadIdx.x;
    if (i < n) p[i] = 0.f;
}

// ---------------- fused MFMA conv block (weights direct from global/L2) ----------------
template<int NTAP, bool NORM, bool PW, bool LRELU, bool RELU, bool STATS>
__global__ void __launch_bounds__(256) k_cv(
        const _Float16* __restrict__ in, const _Float16* __restrict__ W,
        const float* __restrict__ bias, const _Float16* __restrict__ Wp_,
        const float* __restrict__ pbias, const float* __restrict__ stats_in,
        const float* __restrict__ g, const float* __restrict__ bb,
        float* __restrict__ stats_out, _Float16* __restrict__ outp,
        int dil, int ostride) {
    __shared__ _Float16 XT[128][136];
    __shared__ _Float16 Y1[PW?128:1][PW?136:1];
    __shared__ float AffA[NORM?128:1], AffB[NORM?128:1];

    int tid = threadIdx.x;
    int lane = tid & 63;
    int wv = tid >> 6, wm = wv >> 1, wn = wv & 1;
    int ln15 = lane & 15, kh = lane >> 4;
    int t0 = blockIdx.x * 128;
    int nch = blockIdx.y;
    int b = blockIdx.z;
    int ncol0 = nch * 128;
    const _Float16* inb = in + (size_t)b*T_*CH_;
    const _Float16* W_eff = W + (size_t)ncol0*CH_;
    const float* bias_eff = bias + ncol0;

    if (NORM) {
        if (tid < 128) {
            const float invN = 1.f/(float)(B_*T_);
            float s1 = stats_in[tid], s2 = stats_in[128+tid];
            float m = s1*invN, var = s2*invN - m*m;
            float A = rsqrtf(var + 1e-5f) * g[tid];
            AffA[tid] = A; AffB[tid] = bb[tid] - m*A;
        }
    }

    f32x4 acc[4][4];
    f32x4 zero = {0.f,0.f,0.f,0.f};
#pragma unroll
    for (int m = 0; m < 4; ++m)
#pragma unroll
        for (int n = 0; n < 4; ++n) acc[m][n] = zero;

    for (int tap = 0; tap < NTAP; ++tap) {
        int tp = tap;
        if (PW) tp = (tap==0) ? 0 : ((tap==1) ? 2 : 1);   // center tap LAST (kept for residual)
        int off = (tp - NTAP/2)*dil;
        const _Float16* Wt = W_eff + (size_t)tp*CH_*CH_;
        __syncthreads();               // AffA ready (tap0) / XT WAR (tap>0)
#pragma unroll
        for (int q = 0; q < 8; ++q) {
            int idx = tid + q*256;
            int lt = idx >> 4, ck = idx & 15;
            int gt = t0 + lt + off;
            s16x8 v = {0,0,0,0,0,0,0,0};
            bool valid = (gt >= 0 && gt < T_);
            if (valid) {
                v = *(const s16x8*)(inb + (size_t)gt*CH_ + ck*8);
                if (NORM) {
                    union {s16x8 s; f16x8 h;} u; u.s = v;
                    f16x8 r;
#pragma unroll
                    for (int j = 0; j < 8; ++j) {
                        float f = (float)u.h[j];
                        f = fmaf(f, AffA[ck*8+j], AffB[ck*8+j]);
                        r[j] = (_Float16)f;
                    }
                    union {f16x8 h; s16x8 s;} w2; w2.h = r; v = w2.s;
                }
            }
            *(s16x8*)&XT[lt][ck*8] = v;
        }
        __syncthreads();
#pragma unroll
        for (int kt = 0; kt < 4; ++kt) {
            f16x8 af[4], bf[4];
#pragma unroll
            for (int m = 0; m < 4; ++m) af[m] = ldh8(&XT[wm*64+m*16+ln15][kt*32+kh*8]);
#pragma unroll
            for (int n = 0; n < 4; ++n)
                bf[n] = ldh8(Wt + (size_t)(wn*64+n*16+ln15)*CH_ + kt*32 + kh*8);
#pragma unroll
            for (int m = 0; m < 4; ++m)
#pragma unroll
                for (int n = 0; n < 4; ++n)
                    acc[m][n] = __builtin_amdgcn_mfma_f32_16x16x32_f16(af[m], bf[n], acc[m][n], 0,0,0);
        }
    }

    if (PW) {
#pragma unroll
        for (int mf = 0; mf < 4; ++mf)
#pragma unroll
            for (int nf = 0; nf < 4; ++nf) {
                int co = wn*64 + nf*16 + ln15;
                float bv = bias_eff[co];
#pragma unroll
                for (int j = 0; j < 4; ++j) {
                    int tl = wm*64 + mf*16 + kh*4 + j;
                    Y1[tl][co] = (_Float16)(acc[mf][nf][j] + bv);
                }
            }
#pragma unroll
        for (int m = 0; m < 4; ++m)
#pragma unroll
            for (int n = 0; n < 4; ++n) acc[m][n] = zero;
        __syncthreads();
#pragma unroll
        for (int kt = 0; kt < 4; ++kt) {
            f16x8 af[4], bf[4];
#pragma unroll
            for (int m = 0; m < 4; ++m) af[m] = ldh8(&Y1[wm*64+m*16+ln15][kt*32+kh*8]);
#pragma unroll
            for (int n = 0; n < 4; ++n)
                bf[n] = ldh8(Wp_ + (size_t)(wn*64+n*16+ln15)*CH_ + kt*32 + kh*8);
#pragma unroll
            for (int m = 0; m < 4; ++m)
#pragma unroll
                for (int n = 0; n < 4; ++n)
                    acc[m][n] = __builtin_amdgcn_mfma_f32_16x16x32_f16(af[m], bf[n], acc[m][n], 0,0,0);
        }
    }

#pragma unroll
    for (int nf = 0; nf < 4; ++nf) {
        int co = wn*64 + nf*16 + ln15;
        float bfin = PW ? pbias[co] : bias_eff[co];
        float s = 0.f, s2 = 0.f;
#pragma unroll
        for (int mf = 0; mf < 4; ++mf) {
#pragma unroll
            for (int j = 0; j < 4; ++j) {
                int tl = wm*64 + mf*16 + kh*4 + j;
                float v = acc[mf][nf][j] + bfin;
                if (PW) v += (float)XT[tl][co];    // residual = normalized center tile
                if (LRELU) v = v >= 0.f ? v : 0.2f*v;
                if (RELU)  v = fmaxf(v, 0.f);
                outp[((size_t)b*T_ + t0 + tl)*ostride + ncol0 + co] = (_Float16)v;
                if (STATS) { s += v; s2 += v*v; }
            }
        }
        if (STATS) {
            s  += __shfl_down(s, 16);  s  += __shfl_down(s, 32);
            s2 += __shfl_down(s2, 16); s2 += __shfl_down(s2, 32);
            if (kh == 0) {
                atomicAdd(&stats_out[co], s);
                atomicAdd(&stats_out[128+co], s2);
            }
        }
    }
}

// ---------------- transpose static_dict [512][2048] fp32 -> At [2048][512] f16 ----------------
__global__ void k_tr_at(const float* __restrict__ sd, _Float16* __restrict__ At) {
    __shared__ float tile[32][33];
    int tau0 = blockIdx.x*32;
    int c0 = blockIdx.y*32;
    int tx = threadIdx.x, ty = threadIdx.y;
#pragma unroll
    for (int j = 0; j < 4; ++j)
        tile[ty+j*8][tx] = sd[(size_t)(c0+ty+j*8)*ATOM_ + tau0 + tx];
    __syncthreads();
#pragma unroll
    for (int j = 0; j < 4; ++j)
        At[(size_t)(tau0+ty+j*8)*EC_ + c0 + tx] = (_Float16)tile[tx][ty+j*8];
}

// ---------------- GEMM (m97 structure, 4 blocks/CU) + fused anti-diagonal ----------------
// out[b][tau+s] += At[tau][c] * enc[b][s][c] ; 128x128 tile, BK=64, gl_lds staging
__global__ void __launch_bounds__(256, 4) k_gemm(const _Float16* __restrict__ At,
                                                 const _Float16* __restrict__ enc,
                                                 float* __restrict__ out) {
    __shared__ _Float16 lA[128*64];     // linear — gl_lds dest
    __shared__ _Float16 lB[128*64];
    __shared__ float pt[256];
    int tid = threadIdx.x;
    int lane = tid & 63;
    int wv = tid >> 6;
    int wm = wv >> 1, wn = wv & 1;
    int sT = blockIdx.x;                // FASTEST: 256 consecutive blocks share one At tile
    int tT = blockIdx.y;
    int b  = blockIdx.z;
    const _Float16* Ab = At + (size_t)tT*128*EC_;
    const _Float16* Eb = enc + ((size_t)b*T_ + (size_t)sT*128)*EC_;
    int ln15 = lane & 15, kh = lane >> 4;
    int lrow = lane >> 3;               // staging row-in-chunk 0..7
    int lcol = (lane & 7)*8;            // staging f16 col
    pt[tid] = 0.f;
    f32x4 acc[4][4];
    f32x4 zero = {0.f,0.f,0.f,0.f};
#pragma unroll
    for (int m = 0; m < 4; ++m)
#pragma unroll
        for (int n = 0; n < 4; ++n) acc[m][n] = zero;

    for (int kt = 0; kt < 8; ++kt) {
        int k0 = kt*64;
#pragma unroll
        for (int c = 0; c < 4; ++c) {
            int brow = wv*32 + c*8;
            gl_lds16(Ab + (size_t)(brow + lrow)*EC_ + k0 + lcol, &lA[brow*64]);
            gl_lds16(Eb + (size_t)(brow + lrow)*EC_ + k0 + lcol, &lB[brow*64]);
        }
        __syncthreads();                // drains vmcnt (compiler-inserted)
#pragma unroll
        for (int kk = 0; kk < 2; ++kk) {
            f16x8 af[4], bfr[4];
#pragma unroll
            for (int m = 0; m < 4; ++m)
                af[m] = ldh8(&lA[(wm*64 + m*16 + ln15)*64 + kk*32 + kh*8]);
#pragma unroll
            for (int n = 0; n < 4; ++n)
                bfr[n] = ldh8(&lB[(wn*64 + n*16 + ln15)*64 + kk*32 + kh*8]);
#pragma unroll
            for (int m = 0; m < 4; ++m)
#pragma unroll
                for (int n = 0; n < 4; ++n)
                    acc[m][n] = __builtin_amdgcn_mfma_f32_16x16x32_f16(af[m], bfr[n], acc[m][n], 0, 0, 0);
        }
        __syncthreads();                // WAR before restage
    }

    // anti-diagonal reduce: t_local = tau_local + s_local
#pragma unroll
    for (int mn = 0; mn <= 6; ++mn) {
#pragma unroll
        for (int j = 0; j < 4; ++j) {
            float v = 0.f;
#pragma unroll
            for (int m = 0; m < 4; ++m) {
                int n = mn - m;
                if (n >= 0 && n < 4) v += acc[m][n][j];
            }
            int tl = (wm + wn)*64 + mn*16 + kh*4 + j + ln15;
            unsafeAtomicAdd(&pt[tl], v);
        }
    }
    __syncthreads();
    if (tid < 255) {
        int tg = tT*128 + sT*128 + tid;
        if (tg < T_) unsafeAtomicAdd(&out[(size_t)b*T_ + tg], pt[tid]);
    }
}

__global__ void k_fill(float* __restrict__ out, float val) {
    out[blockIdx.x*256 + threadIdx.x] = val;
}

extern "C" void kernel_launch(void* const* d_in, const int* in_sizes, int n_in,
                              void* d_out, int out_size, void* d_ws, size_t ws_size,
                              hipStream_t stream) {
    const float* x       = (const float*)d_in[0];
    const float* fb_w    = (const float*)d_in[1];
    const float* conv0_w = (const float*)d_in[2];
    const float* conv0_b = (const float*)d_in[3];
    const float* bn0_g   = (const float*)d_in[4];
    const float* bn0_b   = (const float*)d_in[5];
    const float* dil_w   = (const float*)d_in[6];
    const float* dil_b   = (const float*)d_in[7];
    const float* pw_w    = (const float*)d_in[8];
    const float* pw_b    = (const float*)d_in[9];
    const float* bn_g    = (const float*)d_in[10];
    const float* bn_b    = (const float*)d_in[11];
    const float* up_w    = (const float*)d_in[12];
    const float* up_b    = (const float*)d_in[13];
    const float* sdict   = (const float*)d_in[14];
    float* out = (float*)d_out;
    char* ws = (char*)d_ws;

    // layout (bytes)
    const size_t R1   = 33554432;   // spec16 -> enc[0]
    const size_t R2   = 33554432;   // enc[1]  (enc = r1, 67MB contiguous)
    const size_t ACT  = 16777216;   // f16 [b][t][c]
    char* r1   = ws;
    char* actA = ws + R1 + R2;
    char* actB = actA + ACT;
    char* wreg = actB + ACT;
    _Float16* W7   = (_Float16*)wreg;                      // 7*16384
    _Float16* Wd   = W7 + 7*16384;                         // 7*3*16384
    _Float16* Wp   = Wd + 7*3*16384;                       // 7*16384
    _Float16* Wup  = Wp + 7*16384;                         // 65536
    _Float16* Wfb  = Wup + 65536;                          // 65536
    float* stats   = (float*)(Wfb + 65536);                // 8*2*128 floats
    const size_t TOTAL = R1 + R2 + 2*ACT
                       + (7*16384 + 7*3*16384 + 7*16384 + 65536 + 65536)*2 + 8*2*128*4;
    if (ws_size < TOTAL) {
        k_fill<<<(out_size+255)/256, 256, 0, stream>>>(out, 12345.0f);
        return;
    }
    _Float16* spec16 = (_Float16*)r1;
    _Float16* enc = (_Float16*)r1;            // [b][t][c], 67MB (spec16 dead after conv0)
    _Float16* At  = (_Float16*)(actA + 2097152);  // alias in actA (free after conv stack)

    // prep
    k_zero<<<(2048+255)/256, 256, 0, stream>>>(stats, 8*2*128);
    k_pw7<<<(7*16384+255)/256, 256, 0, stream>>>(conv0_w, W7);
    k_pwd<<<(7*3*16384+255)/256, 256, 0, stream>>>(dil_w, Wd);
    k_cast<<<(7*16384+255)/256, 256, 0, stream>>>(pw_w, Wp, 7*16384);
    k_cast<<<(65536+255)/256, 256, 0, stream>>>(up_w, Wup, 65536);
    k_cast<<<(65536+255)/256, 256, 0, stream>>>(fb_w, Wfb, 65536);

    // front: MFMA filter bank, direct time-major f16
    k_fbm<<<dim3(T_/128, B_), 256, 0, stream>>>(x, Wfb, spec16);
    k_cv<7,false,false,true,false,true><<<dim3(T_/128,1,B_), 256, 0, stream>>>(
        spec16, W7, conv0_b, nullptr, nullptr, nullptr, nullptr, nullptr,
        stats + 0, (_Float16*)actA, 1, CH_);

    const int DILS[7] = {1, 3, 9, 27, 81, 243, 1};
    _Float16* cur = (_Float16*)actA;
    _Float16* nxt = (_Float16*)actB;
    for (int i = 0; i < 7; ++i) {
        const float* gi = (i == 0) ? bn0_g : bn_g + (i-1)*CH_;
        const float* bi = (i == 0) ? bn0_b : bn_b + (i-1)*CH_;
        k_cv<3,true,true,true,false,true><<<dim3(T_/128,1,B_), 256, 0, stream>>>(
            cur, Wd + (size_t)i*3*CH_*CH_, dil_b + i*CH_, Wp + (size_t)i*CH_*CH_,
            pw_b + i*CH_, stats + i*256, gi, bi, stats + (i+1)*256, nxt, DILS[i], CH_);
        _Float16* sw = cur; cur = nxt; nxt = sw;
    }
    // cur == actB; actA free -> At alias valid; r1/r2 free for enc (both batches)

    k_tr_at<<<dim3(ATOM_/32, EC_/32), dim3(32,8), 0, stream>>>(sdict, At);
    // up-projection + relu -> enc[b][t][c] f16 (both batches)
    k_cv<1,true,false,false,true,false><<<dim3(T_/128,EC_/128,B_), 256, 0, stream>>>(
        cur, Wup, up_b, nullptr, nullptr,
        stats + 7*256, bn_g + 6*CH_, bn_b + 6*CH_, nullptr, enc, 1, EC_);

    // dictionary conv: zero out, then GEMM with fused anti-diagonal atomics
    k_zero<<<(B_*T_+255)/256, 256, 0, stream>>>(out, B_*T_);
    k_gemm<<<dim3(T_/128, ATOM_/128, B_), 256, 0, stream>>>(At, enc, out);
}